// Round 1
// baseline (275.367 us; speedup 1.0000x reference)
//
#include <hip/hip_runtime.h>
#include <math.h>

// 31x31 depthwise Gaussian (sigma=3) == separable 25-tap Gaussian applied
// twice (outer 3 taps of the 31 are exactly zero). Reflection effectively at
// radius 12 (reference pads 15 but the outer taps are zero).
//
// R4: delete the `raw` LDS staging entirely. rocprof on R3 showed 24% of
// cycles in LDS bank-conflict stalls (phase-B ds_read_b128 was 8-way
// quad-bank conflicted) and occupancy capped at 41% by 37 KB LDS/block.
// The horizontal pass now reads its 32-float window straight from global
// (L1/L2-resident: tile is 21 KB and shared with neighbors), writes `mid`
// to LDS (conflict-free 2-way patterns on both sides), one barrier total.
// LDS drops to 14.6 KB -> 8 blocks/CU (wave-slot limited), conflicts ~0.

#define IW 512
#define IH 512
#define RAD 12
#define TW 64                 // output tile width
#define TH 32                 // output tile height
#define RROWS (TH + 2*RAD)    // 56 mid rows
#define MSTRIDE 65            // 65%32==1 -> conflict-free columns
#define NTASKB (RROWS * 8)    // 448 horizontal tasks (8 outputs each)

__global__ __launch_bounds__(256)
void gauss_blur_sep3_kernel(const float* __restrict__ x,
                            const float* __restrict__ wgt,
                            float* __restrict__ out)
{
    __shared__ float mid[RROWS * MSTRIDE];   // 3640 floats = 14560 B

    const int tid = threadIdx.x;
    const int z   = blockIdx.z;
    const int ch  = z % 3;

    // 1D kernel from 2D weight, computed per-thread (uniform broadcast loads,
    // no LDS, no barrier): k1[t] = w2d[15][3+t] / sqrt(w2d[15][15]).
    float kk[13];
    {
        const float* __restrict__ wp = wgt + ch * 961 + 15 * 31;
        const float inv = 1.0f / sqrtf(wp[15]);
#pragma unroll
        for (int t = 0; t < 13; ++t) kk[t] = wp[3 + t] * inv;
    }

    const int r0g = blockIdx.y * TH;
    const int c0g = blockIdx.x * TW;
    const float* __restrict__ src = x + (size_t)z * (IW * IH);

    // ---------- phase B: horizontal pass, global -> LDS mid -----------------
    // 448 tasks = 56 rows x 8 groups of 8 outputs. Task (m,g) reads global
    // row reflect(r0g+m-12), cols gc0..gc0+31 (gc0 = c0g+8g-12, float4
    // aligned), and writes mid[m][8g..8g+8). Interior: 8 dwordx4 loads off
    // one base (immediate offsets). Edge cols (only x-edge blocks, g in
    // {0,1,6,7}): scalar gather with reflect.
#pragma unroll
    for (int i = 0; i < 2; ++i) {
        const int task = tid + i * 256;
        if (i == 0 || task < NTASKB) {          // i==1: tid<192, wave-uniform
            const int g = task & 7;
            const int m = task >> 3;
            int gr = r0g + m - RAD;
            gr = gr < 0 ? -gr : (gr >= IH ? 2 * IH - 2 - gr : gr);
            const float* __restrict__ rp = src + (size_t)gr * IW;
            const int gc0 = c0g + 8 * g - RAD;
            float v[32];
            if (gc0 >= 0 && gc0 <= IW - 32) {
#pragma unroll
                for (int q = 0; q < 8; ++q) {
                    const float4 f = *(const float4*)(rp + gc0 + 4 * q);
                    v[4*q+0] = f.x; v[4*q+1] = f.y; v[4*q+2] = f.z; v[4*q+3] = f.w;
                }
            } else {
#pragma unroll
                for (int j = 0; j < 32; ++j) {
                    int cc = gc0 + j;
                    cc = cc < 0 ? -cc : (cc >= IW ? 2 * IW - 2 - cc : cc);
                    v[j] = rp[cc];
                }
            }
#pragma unroll
            for (int o = 0; o < 8; ++o) {
                float acc = v[o + 12] * kk[12];
#pragma unroll
                for (int t = 0; t < 12; ++t)
                    acc = fmaf(v[o + t] + v[o + 24 - t], kk[t], acc);
                // banks: (65m+8g+o)%32 = (m+8g+o)%32 -> exact 2-way, free
                mid[m * MSTRIDE + 8 * g + o] = acc;
            }
        }
    }
    __syncthreads();

    // ---------- phase D: vertical sliding-window pass, coalesced stores -----
    // lanes span 64 contiguous cols (conflict-free LDS, coalesced stores);
    // each thread: 1 col x 8 rows, 32 LDS reads feed 200 FMAs.
    const int c  = tid & 63;
    const int rb = (tid >> 6) * 8;

    float acc[8];
#pragma unroll
    for (int o = 0; o < 8; ++o) acc[o] = 0.f;

#pragma unroll
    for (int m2 = 0; m2 < 32; ++m2) {
        const float vv = mid[(rb + m2) * MSTRIDE + c];
#pragma unroll
        for (int o = 0; o < 8; ++o) {
            const int t = m2 - o;                     // compile-time after unroll
            if (t >= 0 && t < 25) {
                const float w = (t <= 12) ? kk[t] : kk[24 - t];
                acc[o] = fmaf(vv, w, acc[o]);
            }
        }
    }

    float* __restrict__ dst = out + (size_t)z * (IW * IH)
                            + (size_t)(r0g + rb) * IW + c0g + c;
#pragma unroll
    for (int o = 0; o < 8; ++o) {
        dst[(size_t)o * IW] = acc[o];
    }
}

extern "C" void kernel_launch(void* const* d_in, const int* in_sizes, int n_in,
                              void* d_out, int out_size, void* d_ws, size_t ws_size,
                              hipStream_t stream)
{
    const float* x   = (const float*)d_in[0];
    const float* wgt = (const float*)d_in[1];
    float* out = (float*)d_out;

    dim3 grid(IW / TW, IH / TH, 96);   // 8 x 16 x 96 = 12288 blocks
    gauss_blur_sep3_kernel<<<grid, dim3(256), 0, stream>>>(x, wgt, out);
}

// Round 2
// 199.790 us; speedup vs baseline: 1.3783x; 1.3783x over previous
//
#include <hip/hip_runtime.h>
#include <math.h>

// 31x31 depthwise Gaussian (sigma=3) == separable 25-tap Gaussian applied
// twice (outer 3 taps of the 31 are exactly zero). Reflection effectively at
// radius 12 (reference pads 15 but the outer taps are zero).
//
// R5: vertical-first separable structure.
//   - R3 (126us): raw-tile LDS staging; 24% of cycles lost to 8-way b128
//     bank conflicts in the horizontal pass, occupancy capped 41% by 37KB LDS.
//   - R4 (160us): global-read horizontal pass; lanes at 32B stride across 8
//     rows -> each dwordx4 touches ~36 cache lines -> TA/L1 serialization.
//   - R5: do the VERTICAL pass from global (consecutive lanes = consecutive
//     columns -> perfectly coalesced scalar loads, 32 independent loads in
//     flight per thread), write the 32x96 intermediate to LDS (conflict-free),
//     then the horizontal pass reads LDS at exact-2-way (free) and stores
//     coalesced. One barrier, 12.4KB LDS -> 8 blocks/CU (wave-slot cap).

#define IW 512
#define IH 512
#define RAD 12
#define TW 64                 // output tile width
#define TH 32                 // output tile height
#define MCOLS 96              // staged mid cols: c0-16 .. c0+79 (need c0-12..c0+75)
#define MSTRIDE 97            // 97%32==1 -> conflict-free / exact-2-way patterns
#define NTASKV (MCOLS * 4)    // 384 vertical tasks (8 output rows each)

__global__ __launch_bounds__(256)
void gauss_blur_sep3_kernel(const float* __restrict__ x,
                            const float* __restrict__ wgt,
                            float* __restrict__ out)
{
    __shared__ float mid[TH * MSTRIDE];   // 3104 floats = 12416 B

    const int tid = threadIdx.x;
    const int z   = blockIdx.z;
    const int ch  = z % 3;

    // 1D kernel from 2D weight (uniform per block -> scalar loads):
    // k1[t] = w2d[15][3+t] / sqrt(w2d[15][15]), symmetric, t=0..12 held.
    float kk[13];
    {
        const float* __restrict__ wp = wgt + ch * 961 + 15 * 31;
        const float inv = 1.0f / sqrtf(wp[15]);
#pragma unroll
        for (int t = 0; t < 13; ++t) kk[t] = wp[3 + t] * inv;
    }

    const int r0g = blockIdx.y * TH;
    const int c0g = blockIdx.x * TW;
    const float* __restrict__ src = x + (size_t)z * (IW * IH);

    // ---------- phase V: vertical pass, global -> LDS mid -------------------
    // task (cp, rb): column c0g-16+cp (reflected once), output rows
    // r0g+8rb .. +7, input rows r0g+8rb-12 .. +19 (32 coalesced loads).
#pragma unroll
    for (int i = 0; i < 2; ++i) {
        const int task = tid + i * 256;
        if (i == 0 || task < NTASKV) {        // i==1: tid<128, wave-uniform
            const int rb = task / MCOLS;
            const int cp = task - rb * MCOLS;
            int gc = c0g - 16 + cp;
            gc = gc < 0 ? -gc : (gc >= IW ? 2 * IW - 2 - gc : gc);
            const int first = r0g + 8 * rb - RAD;

            float v[32];
            if (first >= 0 && first + 31 < IH) {
                const float* __restrict__ p = src + (size_t)first * IW + gc;
#pragma unroll
                for (int j = 0; j < 32; ++j) v[j] = p[(size_t)j * IW];
            } else {
#pragma unroll
                for (int j = 0; j < 32; ++j) {
                    int gr = first + j;
                    gr = gr < 0 ? -gr : (gr >= IH ? 2 * IH - 2 - gr : gr);
                    v[j] = src[(size_t)gr * IW + gc];
                }
            }
#pragma unroll
            for (int o = 0; o < 8; ++o) {
                float acc = v[o + 12] * kk[12];
#pragma unroll
                for (int t = 0; t < 12; ++t)
                    acc = fmaf(v[o + t] + v[o + 24 - t], kk[t], acc);
                // banks: ((8rb+o)*97 + cp)%32 -> cp consecutive: conflict-free
                mid[(8 * rb + o) * MSTRIDE + cp] = acc;
            }
        }
    }
    __syncthreads();

    // ---------- phase H: horizontal pass, LDS -> out ------------------------
    // task (r, g): row r, output cols c0g+8g .. +7; reads mid[r][8g+4+j],
    // bank = (r + 8g + 4 + j)%32 -> exact 2-way (free). Stores: wave covers
    // 8 rows x 128B contiguous per row.
    const int g = tid & 7;
    const int r = tid >> 3;
    {
        const float* __restrict__ mrow = &mid[r * MSTRIDE + 8 * g + 4];
        float v[32];
#pragma unroll
        for (int j = 0; j < 32; ++j) v[j] = mrow[j];

        float acc[8];
#pragma unroll
        for (int o = 0; o < 8; ++o) {
            float a = v[o + 12] * kk[12];
#pragma unroll
            for (int t = 0; t < 12; ++t)
                a = fmaf(v[o + t] + v[o + 24 - t], kk[t], a);
            acc[o] = a;
        }

        float* __restrict__ dst = out + (size_t)z * (IW * IH)
                                + (size_t)(r0g + r) * IW + c0g + 8 * g;
        *(float4*)(dst + 0) = make_float4(acc[0], acc[1], acc[2], acc[3]);
        *(float4*)(dst + 4) = make_float4(acc[4], acc[5], acc[6], acc[7]);
    }
}

extern "C" void kernel_launch(void* const* d_in, const int* in_sizes, int n_in,
                              void* d_out, int out_size, void* d_ws, size_t ws_size,
                              hipStream_t stream)
{
    const float* x   = (const float*)d_in[0];
    const float* wgt = (const float*)d_in[1];
    float* out = (float*)d_out;

    dim3 grid(IW / TW, IH / TH, 96);   // 8 x 16 x 96 = 12288 blocks
    gauss_blur_sep3_kernel<<<grid, dim3(256), 0, stream>>>(x, wgt, out);
}